// Round 1
// baseline (1031.699 us; speedup 1.0000x reference)
//
#include <hip/hip_runtime.h>

// SSM selective scan: h_t = A_t*h_{t-1} + B_t*x_t (elementwise over [b,d,n]),
// y_t = sum_n C_t[n] * h_t[d,n].
// B=4, S=2048, D=768, N=16, all float32.
//
// Design: one thread per (b,d,n) chain; block = 64 threads = 1 wave = 4 d x 16 n.
// 768 blocks = 3 blocks/CU. Serial dependence over s handled per-thread; HBM
// latency hidden by a depth-8 rolling register prefetch (loads are independent
// of the h-chain). All prefetch-buffer indices are compile-time (unrolled) so
// buffers stay in VGPRs (rule #20).

constexpr int BATCH = 4;
constexpr int SEQ   = 2048;
constexpr int DDIM  = 768;
constexpr int NDIM  = 16;
constexpr int PF    = 8;   // prefetch depth (s-steps ahead)

__global__ __launch_bounds__(64) void ssm_scan_kernel(
    const float* __restrict__ A,
    const float* __restrict__ B,
    const float* __restrict__ C,
    const float* __restrict__ X,
    float* __restrict__ Y)
{
    const int lane = threadIdx.x;          // 0..63
    const int n    = lane & (NDIM - 1);    // 0..15
    const int dl   = lane >> 4;            // 0..3
    const int blk  = blockIdx.x;           // 0..767
    const int b    = blk / (DDIM / 4);
    const int d    = (blk % (DDIM / 4)) * 4 + dl;

    const size_t strideAB = (size_t)DDIM * NDIM;   // elements per s-step in A/B
    const float* pA = A + (size_t)b * SEQ * strideAB + (size_t)d * NDIM + n;
    const float* pB = B + (size_t)b * SEQ * strideAB + (size_t)d * NDIM + n;
    const float* pX = X + (size_t)b * SEQ * DDIM + d;
    const float* pC = C + (size_t)b * SEQ * NDIM + n;
    float*       pY = Y + (size_t)b * SEQ * DDIM + d;

    // Rolling prefetch buffers (statically indexed only).
    float a_v[PF], b_v[PF], x_v[PF], c_v[PF];
#pragma unroll
    for (int i = 0; i < PF; ++i) {
        a_v[i] = pA[(size_t)i * strideAB];
        b_v[i] = pB[(size_t)i * strideAB];
        x_v[i] = pX[(size_t)i * DDIM];
        c_v[i] = pC[(size_t)i * NDIM];
    }

    float h = 0.0f;
    int s0 = 0;
    for (; s0 < SEQ - PF; s0 += PF) {
#pragma unroll
        for (int i = 0; i < PF; ++i) {
            const int s = s0 + i;
            const float av = a_v[i];
            const float bv = b_v[i];
            const float xv = x_v[i];
            const float cv = c_v[i];
            // prefetch s + PF (always in range in this main loop)
            const size_t sp = (size_t)(s + PF);
            a_v[i] = pA[sp * strideAB];
            b_v[i] = pB[sp * strideAB];
            x_v[i] = pX[sp * DDIM];
            c_v[i] = pC[sp * NDIM];

            h = fmaf(av, h, bv * xv);      // serial chain: 1 mul + 1 fma
            float p = cv * h;
            // reduce over the 16-lane n-group (off the serial chain)
            p += __shfl_xor(p, 1);
            p += __shfl_xor(p, 2);
            p += __shfl_xor(p, 4);
            p += __shfl_xor(p, 8);
            if (n == 0) pY[(size_t)s * DDIM] = p;
        }
    }
    // epilogue: last PF steps, no prefetch
#pragma unroll
    for (int i = 0; i < PF; ++i) {
        const int s = s0 + i;
        h = fmaf(a_v[i], h, b_v[i] * x_v[i]);
        float p = c_v[i] * h;
        p += __shfl_xor(p, 1);
        p += __shfl_xor(p, 2);
        p += __shfl_xor(p, 4);
        p += __shfl_xor(p, 8);
        if (n == 0) pY[(size_t)s * DDIM] = p;
    }
}

extern "C" void kernel_launch(void* const* d_in, const int* in_sizes, int n_in,
                              void* d_out, int out_size, void* d_ws, size_t ws_size,
                              hipStream_t stream) {
    const float* A = (const float*)d_in[0];
    const float* B = (const float*)d_in[1];
    const float* C = (const float*)d_in[2];
    const float* X = (const float*)d_in[3];
    float*       Y = (float*)d_out;

    dim3 grid(BATCH * (DDIM / 4));   // 768 blocks, one wave each
    dim3 block(64);
    hipLaunchKernelGGL(ssm_scan_kernel, grid, block, 0, stream, A, B, C, X, Y);
}